// Round 1
// baseline (5409.430 us; speedup 1.0000x reference)
//
#include <hip/hip_runtime.h>
#include <math.h>

#define N_NODES 100000
#define R_REL   3
#define E_EDGES 1600000
#define HID     64
#define DFLAT   129
#define KTOP    30
#define NC1     16
#define NC2     32
#define KSZ     5
#define NG      64
#define CAP     4096
#define SORTN   4096
#define TOUT    11   // K/2 - KS + 1

// ---------------- utility ----------------
__global__ void zero_f32(float* p, int n) {
    int i = blockIdx.x * blockDim.x + threadIdx.x;
    int stride = gridDim.x * blockDim.x;
    for (; i < n; i += stride) p[i] = 0.0f;
}

// ---------------- gcn norm ----------------
__global__ void deg_kernel(const int* dst, const float* ew, float* deg, int e) {
    int i = blockIdx.x * blockDim.x + threadIdx.x;
    if (i < e) atomicAdd(&deg[dst[i]], ew[i]);
}

__global__ void dinv_kernel(const float* deg, float* dinv, int n) {
    int i = blockIdx.x * blockDim.x + threadIdx.x;
    if (i < n) dinv[i] = rsqrtf(deg[i] + 1.0f);   // deg+1 > 0 always (ew >= 0)
}

__global__ void enorm_kernel(const int* src, const int* dst, const float* ew,
                             const float* dinv, float* enorm, int e) {
    int i = blockIdx.x * blockDim.x + threadIdx.x;
    if (i < e) enorm[i] = dinv[src[i]] * ew[i] * dinv[dst[i]];
}

// ---------------- dense: out[n,64] = X[n,Kd] @ W[Kd,64] ----------------
__global__ void gemm_nk64(const float* __restrict__ X, const float* __restrict__ W,
                          float* __restrict__ out, int n, int Kd) {
    int gid = blockIdx.x * blockDim.x + threadIdx.x;
    int row = gid >> 6;
    int c   = gid & 63;
    if (row >= n) return;
    const float* xr = X + (size_t)row * Kd;
    float acc = 0.0f;
    for (int k = 0; k < Kd; ++k) acc += xr[k] * W[k * 64 + c];
    out[(size_t)row * 64 + c] = acc;
}

// ---------------- edge aggregation (64 features, one wave per edge) ----------------
__global__ void scatter64(const int* __restrict__ src, const int* __restrict__ dst,
                          const float* __restrict__ enorm, const float* __restrict__ h,
                          float* __restrict__ agg, int e) {
    int gid = blockIdx.x * blockDim.x + threadIdx.x;
    int edge = gid >> 6;
    int lane = gid & 63;
    if (edge >= e) return;
    int s = src[edge];
    int d = dst[edge];
    float coef = enorm[edge];
    atomicAdd(&agg[(size_t)d * 64 + lane], coef * h[(size_t)s * 64 + lane]);
}

__global__ void finalize64(const float* __restrict__ agg, const float* __restrict__ hpre,
                           const float* __restrict__ dinv, const float* __restrict__ bias,
                           float* __restrict__ out, int n) {
    int gid = blockIdx.x * blockDim.x + threadIdx.x;
    int row = gid >> 6;
    int j   = gid & 63;
    if (row >= n) return;
    float sn = dinv[row] * dinv[row];
    out[gid] = tanhf(agg[gid] + sn * hpre[gid] + bias[j]);
}

// ---------------- h2 @ W2 (64 -> 1), one wave per row ----------------
__global__ void gemv64(const float* __restrict__ h, const float* __restrict__ w,
                       float* __restrict__ out, int n) {
    int gid = blockIdx.x * blockDim.x + threadIdx.x;
    int row = gid >> 6;
    int lane = gid & 63;
    if (row >= n) return;
    float v = h[(size_t)row * 64 + lane] * w[lane];
    for (int off = 32; off > 0; off >>= 1) v += __shfl_down(v, off, 64);
    if (lane == 0) out[row] = v;
}

__global__ void scatter1(const int* __restrict__ src, const int* __restrict__ dst,
                         const float* __restrict__ enorm, const float* __restrict__ h,
                         float* __restrict__ agg, int e) {
    int i = blockIdx.x * blockDim.x + threadIdx.x;
    if (i < e) atomicAdd(&agg[dst[i]], enorm[i] * h[src[i]]);
}

__global__ void finalize1(const float* __restrict__ agg, const float* __restrict__ hpre,
                          const float* __restrict__ dinv, const float* __restrict__ b2,
                          float* __restrict__ out, int n) {
    int i = blockIdx.x * blockDim.x + threadIdx.x;
    if (i < n) {
        float sn = dinv[i] * dinv[i];
        out[i] = tanhf(agg[i] + sn * hpre[i] + b2[0]);
    }
}

// ---------------- group compaction ----------------
__global__ void compact_kernel(const int* __restrict__ group, int* cnt, int* lists, int n) {
    int i = blockIdx.x * blockDim.x + threadIdx.x;
    if (i < n) {
        int g = group[i];
        int p = atomicAdd(&cnt[g], 1);
        if (p < CAP) lists[g * CAP + p] = i;
    }
}

// ---------------- per-group top-K by h3 (desc, tie: lower index) ----------------
__global__ void __launch_bounds__(256) topk_kernel(const int* __restrict__ cnt,
                                                   const int* __restrict__ lists,
                                                   const float* __restrict__ h3,
                                                   int* __restrict__ topk) {
    __shared__ float sval[SORTN];
    __shared__ int   sidx[SORTN];
    int g = blockIdx.x;
    int tid = threadIdx.x;
    int c = cnt[g];
    if (c > CAP) c = CAP;
    for (int t = tid; t < SORTN; t += blockDim.x) {
        if (t < c) {
            int node = lists[g * CAP + t];
            sval[t] = h3[node];
            sidx[t] = node;
        } else {
            sval[t] = -INFINITY;
            sidx[t] = 0x7fffffff;
        }
    }
    // bitonic sort, overall DESCENDING by (value desc, index asc)
    for (int k = 2; k <= SORTN; k <<= 1) {
        for (int j = k >> 1; j > 0; j >>= 1) {
            __syncthreads();
            for (int t = tid; t < SORTN; t += blockDim.x) {
                int l = t ^ j;
                if (l > t) {
                    bool dirDesc = ((t & k) == 0);
                    float v0 = sval[t], v1 = sval[l];
                    int   i0 = sidx[t], i1 = sidx[l];
                    bool aBeforeB = (v0 > v1) || (v0 == v1 && i0 < i1);
                    bool doSwap = dirDesc ? !aBeforeB : aBeforeB;
                    if (doSwap) {
                        sval[t] = v1; sval[l] = v0;
                        sidx[t] = i1; sidx[l] = i0;
                    }
                }
            }
        }
    }
    __syncthreads();
    if (tid < KTOP) topk[g * KTOP + tid] = sidx[tid];
}

// ---------------- fused sort-pool gather + conv1 + maxpool + conv2 ----------------
__global__ void __launch_bounds__(256) pool_conv(const float* __restrict__ h1,
                                                 const float* __restrict__ h2,
                                                 const float* __restrict__ h3,
                                                 const int* __restrict__ topk,
                                                 const float* __restrict__ c1w,
                                                 const float* __restrict__ c1b,
                                                 const float* __restrict__ c2w,
                                                 const float* __restrict__ c2b,
                                                 float* __restrict__ out) {
    __shared__ float sfeat[KTOP * DFLAT];   // 3870
    __shared__ float sy[NC1 * KTOP];        // 480
    __shared__ float sm[NC1 * (KTOP / 2)];  // 240
    int g = blockIdx.x;
    int tid = threadIdx.x;

    for (int t = tid; t < KTOP * DFLAT; t += blockDim.x) {
        int k = t / DFLAT, d = t - k * DFLAT;
        int node = topk[g * KTOP + k];
        float v;
        if (d < 64)        v = h1[(size_t)node * 64 + d];
        else if (d < 128)  v = h2[(size_t)node * 64 + (d - 64)];
        else               v = h3[node];
        sfeat[t] = v;
    }
    __syncthreads();

    for (int t = tid; t < NC1 * KTOP; t += blockDim.x) {
        int c = t / KTOP, k = t - c * KTOP;
        float acc = c1b[c];
        const float* w = c1w + c * DFLAT;
        const float* f = sfeat + k * DFLAT;
        for (int d = 0; d < DFLAT; ++d) acc += f[d] * w[d];
        sy[c * KTOP + k] = fmaxf(acc, 0.0f);
    }
    __syncthreads();

    for (int t = tid; t < NC1 * (KTOP / 2); t += blockDim.x) {
        int c = t / (KTOP / 2), j = t - c * (KTOP / 2);
        sm[t] = fmaxf(sy[c * KTOP + 2 * j], sy[c * KTOP + 2 * j + 1]);
    }
    __syncthreads();

    for (int t = tid; t < NC2 * TOUT; t += blockDim.x) {
        int c2 = t / TOUT, tt = t - c2 * TOUT;
        float acc = c2b[c2];
        for (int c1i = 0; c1i < NC1; ++c1i) {
            const float* w = c2w + (c2 * NC1 + c1i) * KSZ;
            const float* m = sm + c1i * (KTOP / 2) + tt;
            for (int s = 0; s < KSZ; ++s) acc += m[s] * w[s];
        }
        out[g * NC2 * TOUT + t] += fmaxf(acc, 0.0f);
    }
}

// ---------------- host ----------------
static inline size_t align256(size_t x) { return (x + 255) & ~(size_t)255; }

extern "C" void kernel_launch(void* const* d_in, const int* in_sizes, int n_in,
                              void* d_out, int out_size, void* d_ws, size_t ws_size,
                              hipStream_t stream) {
    const float* x       = (const float*)d_in[0];
    const int*   eidx    = (const int*)d_in[1];    // [R,2,E]
    const float* ew      = (const float*)d_in[2];  // [R,E]
    const int*   group   = (const int*)d_in[3];    // [N]
    const float* W0      = (const float*)d_in[4];  // [R,128,64]
    const float* b0      = (const float*)d_in[5];  // [R,64]
    const float* W1      = (const float*)d_in[6];  // [R,64,64]
    const float* b1      = (const float*)d_in[7];  // [R,64]
    const float* W2      = (const float*)d_in[8];  // [R,64,1]
    const float* b2      = (const float*)d_in[9];  // [R,1]
    const float* c1w     = (const float*)d_in[10]; // [16,1,129]
    const float* c1b     = (const float*)d_in[11];
    const float* c2w     = (const float*)d_in[12]; // [32,16,5]
    const float* c2b     = (const float*)d_in[13];
    float* out = (float*)d_out;

    char* ws = (char*)d_ws;
    size_t off = 0;
    float* deg   = (float*)(ws + off); off = align256(off + (size_t)N_NODES * 4);
    float* dinv  = (float*)(ws + off); off = align256(off + (size_t)N_NODES * 4);
    float* enorm = (float*)(ws + off); off = align256(off + (size_t)E_EDGES * 4);
    float* hpre  = (float*)(ws + off); off = align256(off + (size_t)N_NODES * 64 * 4);
    float* agg   = (float*)(ws + off); off = align256(off + (size_t)N_NODES * 64 * 4);
    float* h1    = (float*)(ws + off); off = align256(off + (size_t)N_NODES * 64 * 4);
    float* h2    = (float*)(ws + off); off = align256(off + (size_t)N_NODES * 64 * 4);
    float* hpre3 = (float*)(ws + off); off = align256(off + (size_t)N_NODES * 4);
    float* agg3  = (float*)(ws + off); off = align256(off + (size_t)N_NODES * 4);
    float* h3    = (float*)(ws + off); off = align256(off + (size_t)N_NODES * 4);
    int*   cnt   = (int*)(ws + off);   off = align256(off + (size_t)NG * 4);
    int*   lists = (int*)(ws + off);   off = align256(off + (size_t)NG * CAP * 4);
    int*   topk  = (int*)(ws + off);   off = align256(off + (size_t)NG * KTOP * 4);
    (void)ws_size;

    const int B = 256;
    const int nOut = NG * NC2 * TOUT;                 // 22528
    const int gN   = (N_NODES + B - 1) / B;           // 391
    const int gE   = (E_EDGES + B - 1) / B;           // 6250
    const int gN64 = (N_NODES * 64 + B - 1) / B;      // 25000
    const int gE64 = (int)(((size_t)E_EDGES * 64 + B - 1) / B); // 400000

    zero_f32<<<(nOut + B - 1) / B, B, 0, stream>>>(out, nOut);

    for (int r = 0; r < R_REL; ++r) {
        const int* src = eidx + (size_t)r * 2 * E_EDGES;
        const int* dst = src + E_EDGES;
        const float* ewr = ew + (size_t)r * E_EDGES;

        zero_f32<<<gN, B, 0, stream>>>(deg, N_NODES);
        deg_kernel<<<gE, B, 0, stream>>>(dst, ewr, deg, E_EDGES);
        dinv_kernel<<<gN, B, 0, stream>>>(deg, dinv, N_NODES);
        enorm_kernel<<<gE, B, 0, stream>>>(src, dst, ewr, dinv, enorm, E_EDGES);

        // layer 1: x[ N,128 ] @ W0 -> h1
        gemm_nk64<<<gN64, B, 0, stream>>>(x, W0 + (size_t)r * 128 * 64, hpre, N_NODES, 128);
        zero_f32<<<gN64, B, 0, stream>>>(agg, N_NODES * 64);
        scatter64<<<gE64, B, 0, stream>>>(src, dst, enorm, hpre, agg, E_EDGES);
        finalize64<<<gN64, B, 0, stream>>>(agg, hpre, dinv, b0 + (size_t)r * 64, h1, N_NODES);

        // layer 2: h1 @ W1 -> h2
        gemm_nk64<<<gN64, B, 0, stream>>>(h1, W1 + (size_t)r * 64 * 64, hpre, N_NODES, 64);
        zero_f32<<<gN64, B, 0, stream>>>(agg, N_NODES * 64);
        scatter64<<<gE64, B, 0, stream>>>(src, dst, enorm, hpre, agg, E_EDGES);
        finalize64<<<gN64, B, 0, stream>>>(agg, hpre, dinv, b1 + (size_t)r * 64, h2, N_NODES);

        // layer 3: h2 @ W2 -> h3 (1 feature)
        gemv64<<<gN64, B, 0, stream>>>(h2, W2 + (size_t)r * 64, hpre3, N_NODES);
        zero_f32<<<gN, B, 0, stream>>>(agg3, N_NODES);
        scatter1<<<gE, B, 0, stream>>>(src, dst, enorm, hpre3, agg3, E_EDGES);
        finalize1<<<gN, B, 0, stream>>>(agg3, hpre3, dinv, b2 + r, h3, N_NODES);

        // sort pooling + convs
        zero_f32<<<1, B, 0, stream>>>((float*)cnt, NG);
        compact_kernel<<<gN, B, 0, stream>>>(group, cnt, lists, N_NODES);
        topk_kernel<<<NG, B, 0, stream>>>(cnt, lists, h3, topk);
        pool_conv<<<NG, B, 0, stream>>>(h1, h2, h3, topk, c1w, c1b, c2w, c2b, out);
    }
}

// Round 2
// 4246.296 us; speedup vs baseline: 1.2739x; 1.2739x over previous
//
#include <hip/hip_runtime.h>
#include <math.h>

#define N_NODES 100000
#define R_REL   3
#define E_EDGES 1600000
#define HID     64
#define DFLAT   129
#define KTOP    30
#define NC1     16
#define NC2     32
#define KSZ     5
#define NG      64
#define CAP     4096
#define SORTN   4096
#define TOUT    11   // K/2 - KS + 1

// ---------------- utility ----------------
__global__ void zero_f32(float* p, int n) {
    int i = blockIdx.x * blockDim.x + threadIdx.x;
    int stride = gridDim.x * blockDim.x;
    for (; i < n; i += stride) p[i] = 0.0f;
}

// ---------------- gcn norm ----------------
__global__ void deg_kernel(const int* dst, const float* ew, float* deg, int e) {
    int i = blockIdx.x * blockDim.x + threadIdx.x;
    if (i < e) atomicAdd(&deg[dst[i]], ew[i]);
}

__global__ void dinv_kernel(const float* deg, float* dinv, int n) {
    int i = blockIdx.x * blockDim.x + threadIdx.x;
    if (i < n) dinv[i] = rsqrtf(deg[i] + 1.0f);
}

__global__ void enorm_kernel(const int* src, const int* dst, const float* ew,
                             const float* dinv, float* enorm, int e) {
    int i = blockIdx.x * blockDim.x + threadIdx.x;
    if (i < e) enorm[i] = dinv[src[i]] * ew[i] * dinv[dst[i]];
}

// ---------------- register-tiled GEMM: out[n,64] = X[n,Kd] @ W[Kd,64] ----------
// 256 threads/block. Thread layout: cq = tid>>6 (wave-uniform column quarter,
// 16 cols), rg = tid&63 (row group of 4 rows). Block covers 256 rows.
// W staged in LDS; per k-step each thread reads 4 float4 of W (broadcast,
// conflict-free since cq is wave-uniform) and does 64 FMAs -> 1 B/FMA.
template<int Kd>
__global__ void __launch_bounds__(256) gemm_tile(const float* __restrict__ X,
                                                 const float* __restrict__ W,
                                                 float* __restrict__ out, int n) {
    __shared__ float sW[Kd * 64];
    const int tid = threadIdx.x;
    for (int t = tid; t < Kd * 16; t += 256)
        ((float4*)sW)[t] = ((const float4*)W)[t];
    __syncthreads();

    const int cq = tid >> 6;          // 0..3, wave-uniform
    const int rg = tid & 63;          // 0..63
    const int row0 = blockIdx.x * 256 + rg * 4;
    const float4* sW4 = (const float4*)sW;   // [Kd][16]

    float4 acc[4][4];
    #pragma unroll
    for (int r = 0; r < 4; ++r)
        #pragma unroll
        for (int c = 0; c < 4; ++c) acc[r][c] = make_float4(0.f, 0.f, 0.f, 0.f);

    int rl[4];
    #pragma unroll
    for (int r = 0; r < 4; ++r) {
        int rr = row0 + r;
        rl[r] = rr < n ? rr : (n - 1);
    }

    for (int k0 = 0; k0 < Kd; k0 += 8) {
        float4 xa[4][2];
        #pragma unroll
        for (int r = 0; r < 4; ++r) {
            const float4* xp = (const float4*)(X + (size_t)rl[r] * Kd + k0);
            xa[r][0] = xp[0];
            xa[r][1] = xp[1];
        }
        #pragma unroll
        for (int kk = 0; kk < 8; ++kk) {
            float xk[4];
            #pragma unroll
            for (int r = 0; r < 4; ++r) {
                float4 h = xa[r][kk >> 2];
                xk[r] = (kk & 3) == 0 ? h.x : (kk & 3) == 1 ? h.y : (kk & 3) == 2 ? h.z : h.w;
            }
            #pragma unroll
            for (int c = 0; c < 4; ++c) {
                float4 w4 = sW4[(k0 + kk) * 16 + cq * 4 + c];
                #pragma unroll
                for (int r = 0; r < 4; ++r) {
                    acc[r][c].x += xk[r] * w4.x;
                    acc[r][c].y += xk[r] * w4.y;
                    acc[r][c].z += xk[r] * w4.z;
                    acc[r][c].w += xk[r] * w4.w;
                }
            }
        }
    }

    #pragma unroll
    for (int r = 0; r < 4; ++r) {
        int rr = row0 + r;
        if (rr < n) {
            float4* op = (float4*)(out + (size_t)rr * 64 + cq * 16);
            #pragma unroll
            for (int c = 0; c < 4; ++c) op[c] = acc[r][c];
        }
    }
}

// ---------------- edge aggregation (64 features, one wave per edge) ----------------
__global__ void scatter64(const int* __restrict__ src, const int* __restrict__ dst,
                          const float* __restrict__ enorm, const float* __restrict__ h,
                          float* __restrict__ agg, int e) {
    int gid = blockIdx.x * blockDim.x + threadIdx.x;
    int edge = gid >> 6;
    int lane = gid & 63;
    if (edge >= e) return;
    int s = src[edge];
    int d = dst[edge];
    float coef = enorm[edge];
    atomicAdd(&agg[(size_t)d * 64 + lane], coef * h[(size_t)s * 64 + lane]);
}

__global__ void finalize64(const float* __restrict__ agg, const float* __restrict__ hpre,
                           const float* __restrict__ dinv, const float* __restrict__ bias,
                           float* __restrict__ out, int n) {
    int gid = blockIdx.x * blockDim.x + threadIdx.x;
    int row = gid >> 6;
    int j   = gid & 63;
    if (row >= n) return;
    float sn = dinv[row] * dinv[row];
    out[gid] = tanhf(agg[gid] + sn * hpre[gid] + bias[j]);
}

// ---------------- h2 @ W2 (64 -> 1), one wave per row ----------------
__global__ void gemv64(const float* __restrict__ h, const float* __restrict__ w,
                       float* __restrict__ out, int n) {
    int gid = blockIdx.x * blockDim.x + threadIdx.x;
    int row = gid >> 6;
    int lane = gid & 63;
    if (row >= n) return;
    float v = h[(size_t)row * 64 + lane] * w[lane];
    for (int off = 32; off > 0; off >>= 1) v += __shfl_down(v, off, 64);
    if (lane == 0) out[row] = v;
}

__global__ void scatter1(const int* __restrict__ src, const int* __restrict__ dst,
                         const float* __restrict__ enorm, const float* __restrict__ h,
                         float* __restrict__ agg, int e) {
    int i = blockIdx.x * blockDim.x + threadIdx.x;
    if (i < e) atomicAdd(&agg[dst[i]], enorm[i] * h[src[i]]);
}

__global__ void finalize1(const float* __restrict__ agg, const float* __restrict__ hpre,
                          const float* __restrict__ dinv, const float* __restrict__ b2,
                          float* __restrict__ out, int n) {
    int i = blockIdx.x * blockDim.x + threadIdx.x;
    if (i < n) {
        float sn = dinv[i] * dinv[i];
        out[i] = tanhf(agg[i] + sn * hpre[i] + b2[0]);
    }
}

// ---------------- group compaction ----------------
__global__ void compact_kernel(const int* __restrict__ group, int* cnt, int* lists, int n) {
    int i = blockIdx.x * blockDim.x + threadIdx.x;
    if (i < n) {
        int g = group[i];
        int p = atomicAdd(&cnt[g], 1);
        if (p < CAP) lists[g * CAP + p] = i;
    }
}

// ---------------- per-group top-K by h3 (desc, tie: lower index) ----------------
__global__ void __launch_bounds__(256) topk_kernel(const int* __restrict__ cnt,
                                                   const int* __restrict__ lists,
                                                   const float* __restrict__ h3,
                                                   int* __restrict__ topk) {
    __shared__ float sval[SORTN];
    __shared__ int   sidx[SORTN];
    int g = blockIdx.x;
    int tid = threadIdx.x;
    int c = cnt[g];
    if (c > CAP) c = CAP;
    for (int t = tid; t < SORTN; t += blockDim.x) {
        if (t < c) {
            int node = lists[g * CAP + t];
            sval[t] = h3[node];
            sidx[t] = node;
        } else {
            sval[t] = -INFINITY;
            sidx[t] = 0x7fffffff;
        }
    }
    for (int k = 2; k <= SORTN; k <<= 1) {
        for (int j = k >> 1; j > 0; j >>= 1) {
            __syncthreads();
            for (int t = tid; t < SORTN; t += blockDim.x) {
                int l = t ^ j;
                if (l > t) {
                    bool dirDesc = ((t & k) == 0);
                    float v0 = sval[t], v1 = sval[l];
                    int   i0 = sidx[t], i1 = sidx[l];
                    bool aBeforeB = (v0 > v1) || (v0 == v1 && i0 < i1);
                    bool doSwap = dirDesc ? !aBeforeB : aBeforeB;
                    if (doSwap) {
                        sval[t] = v1; sval[l] = v0;
                        sidx[t] = i1; sidx[l] = i0;
                    }
                }
            }
        }
    }
    __syncthreads();
    if (tid < KTOP) topk[g * KTOP + tid] = sidx[tid];
}

// ---------------- fused sort-pool gather + conv1 + maxpool + conv2 ----------------
__global__ void __launch_bounds__(256) pool_conv(const float* __restrict__ h1,
                                                 const float* __restrict__ h2,
                                                 const float* __restrict__ h3,
                                                 const int* __restrict__ topk,
                                                 const float* __restrict__ c1w,
                                                 const float* __restrict__ c1b,
                                                 const float* __restrict__ c2w,
                                                 const float* __restrict__ c2b,
                                                 float* __restrict__ out) {
    __shared__ float sfeat[KTOP * DFLAT];
    __shared__ float sy[NC1 * KTOP];
    __shared__ float sm[NC1 * (KTOP / 2)];
    int g = blockIdx.x;
    int tid = threadIdx.x;

    for (int t = tid; t < KTOP * DFLAT; t += blockDim.x) {
        int k = t / DFLAT, d = t - k * DFLAT;
        int node = topk[g * KTOP + k];
        float v;
        if (d < 64)        v = h1[(size_t)node * 64 + d];
        else if (d < 128)  v = h2[(size_t)node * 64 + (d - 64)];
        else               v = h3[node];
        sfeat[t] = v;
    }
    __syncthreads();

    for (int t = tid; t < NC1 * KTOP; t += blockDim.x) {
        int c = t / KTOP, k = t - c * KTOP;
        float acc = c1b[c];
        const float* w = c1w + c * DFLAT;
        const float* f = sfeat + k * DFLAT;
        for (int d = 0; d < DFLAT; ++d) acc += f[d] * w[d];
        sy[c * KTOP + k] = fmaxf(acc, 0.0f);
    }
    __syncthreads();

    for (int t = tid; t < NC1 * (KTOP / 2); t += blockDim.x) {
        int c = t / (KTOP / 2), j = t - c * (KTOP / 2);
        sm[t] = fmaxf(sy[c * KTOP + 2 * j], sy[c * KTOP + 2 * j + 1]);
    }
    __syncthreads();

    for (int t = tid; t < NC2 * TOUT; t += blockDim.x) {
        int c2 = t / TOUT, tt = t - c2 * TOUT;
        float acc = c2b[c2];
        for (int c1i = 0; c1i < NC1; ++c1i) {
            const float* w = c2w + (c2 * NC1 + c1i) * KSZ;
            const float* m = sm + c1i * (KTOP / 2) + tt;
            for (int s = 0; s < KSZ; ++s) acc += m[s] * w[s];
        }
        out[g * NC2 * TOUT + t] += fmaxf(acc, 0.0f);
    }
}

// ---------------- host ----------------
static inline size_t align256(size_t x) { return (x + 255) & ~(size_t)255; }

extern "C" void kernel_launch(void* const* d_in, const int* in_sizes, int n_in,
                              void* d_out, int out_size, void* d_ws, size_t ws_size,
                              hipStream_t stream) {
    const float* x       = (const float*)d_in[0];
    const int*   eidx    = (const int*)d_in[1];    // [R,2,E]
    const float* ew      = (const float*)d_in[2];  // [R,E]
    const int*   group   = (const int*)d_in[3];    // [N]
    const float* W0      = (const float*)d_in[4];  // [R,128,64]
    const float* b0      = (const float*)d_in[5];
    const float* W1      = (const float*)d_in[6];  // [R,64,64]
    const float* b1      = (const float*)d_in[7];
    const float* W2      = (const float*)d_in[8];  // [R,64,1]
    const float* b2      = (const float*)d_in[9];
    const float* c1w     = (const float*)d_in[10];
    const float* c1b     = (const float*)d_in[11];
    const float* c2w     = (const float*)d_in[12];
    const float* c2b     = (const float*)d_in[13];
    float* out = (float*)d_out;

    char* ws = (char*)d_ws;
    size_t off = 0;
    float* deg   = (float*)(ws + off); off = align256(off + (size_t)N_NODES * 4);
    float* dinv  = (float*)(ws + off); off = align256(off + (size_t)N_NODES * 4);
    float* enorm = (float*)(ws + off); off = align256(off + (size_t)E_EDGES * 4);
    float* hpre  = (float*)(ws + off); off = align256(off + (size_t)N_NODES * 64 * 4);
    float* agg   = (float*)(ws + off); off = align256(off + (size_t)N_NODES * 64 * 4);
    float* h1    = (float*)(ws + off); off = align256(off + (size_t)N_NODES * 64 * 4);
    float* h2    = (float*)(ws + off); off = align256(off + (size_t)N_NODES * 64 * 4);
    float* hpre3 = (float*)(ws + off); off = align256(off + (size_t)N_NODES * 4);
    float* agg3  = (float*)(ws + off); off = align256(off + (size_t)N_NODES * 4);
    float* h3    = (float*)(ws + off); off = align256(off + (size_t)N_NODES * 4);
    int*   cnt   = (int*)(ws + off);   off = align256(off + (size_t)NG * 4);
    int*   lists = (int*)(ws + off);   off = align256(off + (size_t)NG * CAP * 4);
    int*   topk  = (int*)(ws + off);   off = align256(off + (size_t)NG * KTOP * 4);
    (void)ws_size;

    const int B = 256;
    const int nOut = NG * NC2 * TOUT;
    const int gN   = (N_NODES + B - 1) / B;
    const int gE   = (E_EDGES + B - 1) / B;
    const int gN64 = (N_NODES * 64 + B - 1) / B;
    const int gE64 = (int)(((size_t)E_EDGES * 64 + B - 1) / B);
    const int gT   = (N_NODES + 255) / 256;   // gemm_tile: 256 rows/block

    zero_f32<<<(nOut + B - 1) / B, B, 0, stream>>>(out, nOut);

    for (int r = 0; r < R_REL; ++r) {
        const int* src = eidx + (size_t)r * 2 * E_EDGES;
        const int* dst = src + E_EDGES;
        const float* ewr = ew + (size_t)r * E_EDGES;

        zero_f32<<<gN, B, 0, stream>>>(deg, N_NODES);
        deg_kernel<<<gE, B, 0, stream>>>(dst, ewr, deg, E_EDGES);
        dinv_kernel<<<gN, B, 0, stream>>>(deg, dinv, N_NODES);
        enorm_kernel<<<gE, B, 0, stream>>>(src, dst, ewr, dinv, enorm, E_EDGES);

        // layer 1
        gemm_tile<128><<<gT, B, 0, stream>>>(x, W0 + (size_t)r * 128 * 64, hpre, N_NODES);
        zero_f32<<<gN64, B, 0, stream>>>(agg, N_NODES * 64);
        scatter64<<<gE64, B, 0, stream>>>(src, dst, enorm, hpre, agg, E_EDGES);
        finalize64<<<gN64, B, 0, stream>>>(agg, hpre, dinv, b0 + (size_t)r * 64, h1, N_NODES);

        // layer 2
        gemm_tile<64><<<gT, B, 0, stream>>>(h1, W1 + (size_t)r * 64 * 64, hpre, N_NODES);
        zero_f32<<<gN64, B, 0, stream>>>(agg, N_NODES * 64);
        scatter64<<<gE64, B, 0, stream>>>(src, dst, enorm, hpre, agg, E_EDGES);
        finalize64<<<gN64, B, 0, stream>>>(agg, hpre, dinv, b1 + (size_t)r * 64, h2, N_NODES);

        // layer 3
        gemv64<<<gN64, B, 0, stream>>>(h2, W2 + (size_t)r * 64, hpre3, N_NODES);
        zero_f32<<<gN, B, 0, stream>>>(agg3, N_NODES);
        scatter1<<<gE, B, 0, stream>>>(src, dst, enorm, hpre3, agg3, E_EDGES);
        finalize1<<<gN, B, 0, stream>>>(agg3, hpre3, dinv, b2 + r, h3, N_NODES);

        // sort pooling + convs
        zero_f32<<<1, B, 0, stream>>>((float*)cnt, NG);
        compact_kernel<<<gN, B, 0, stream>>>(group, cnt, lists, N_NODES);
        topk_kernel<<<NG, B, 0, stream>>>(cnt, lists, h3, topk);
        pool_conv<<<NG, B, 0, stream>>>(h1, h2, h3, topk, c1w, c1b, c2w, c2b, out);
    }
}

// Round 4
// 2678.919 us; speedup vs baseline: 2.0193x; 1.5851x over previous
//
#include <hip/hip_runtime.h>
#include <math.h>

#define N_NODES 100000
#define R_REL   3
#define E_EDGES 1600000
#define HID     64
#define DFLAT   129
#define KTOP    30
#define NC1     16
#define NC2     32
#define KSZ     5
#define NG      64
#define CAP     4096
#define SORTN   4096
#define TOUT    11   // K/2 - KS + 1

// ---------------- utility ----------------
__global__ void zero_f32(float* p, int n) {
    int i = blockIdx.x * blockDim.x + threadIdx.x;
    int stride = gridDim.x * blockDim.x;
    for (; i < n; i += stride) p[i] = 0.0f;
}

__global__ void zero_i32(int* p, int n) {
    int i = blockIdx.x * blockDim.x + threadIdx.x;
    if (i < n) p[i] = 0;
}

__global__ void copy_i32(const int* a, int* b, int n) {
    int i = blockIdx.x * blockDim.x + threadIdx.x;
    if (i < n) b[i] = a[i];
}

// ---------------- CSR build ----------------
__global__ void hist_kernel(const int* __restrict__ dst, int* __restrict__ cnt, int e) {
    int i = blockIdx.x * blockDim.x + threadIdx.x;
    if (i < e) atomicAdd(&cnt[dst[i]], 1);
}

__global__ void block_sum(const int* __restrict__ cnt, int* __restrict__ bsum, int n) {
    __shared__ int s[256];
    int i = blockIdx.x * 256 + threadIdx.x;
    s[threadIdx.x] = i < n ? cnt[i] : 0;
    __syncthreads();
    for (int o = 128; o > 0; o >>= 1) {
        if (threadIdx.x < o) s[threadIdx.x] += s[threadIdx.x + o];
        __syncthreads();
    }
    if (threadIdx.x == 0) bsum[blockIdx.x] = s[0];
}

// single block, 512 threads: in-place exclusive scan of bsum[0..nb)
__global__ void __launch_bounds__(512) scan_bsum(int* bsum, int nb) {
    __shared__ int s[512];
    int t = threadIdx.x;
    int orig = t < nb ? bsum[t] : 0;
    s[t] = orig;
    __syncthreads();
    for (int o = 1; o < 512; o <<= 1) {
        int v = t >= o ? s[t - o] : 0;
        __syncthreads();
        s[t] += v;
        __syncthreads();
    }
    if (t < nb) bsum[t] = s[t] - orig;   // exclusive
}

__global__ void scan_blocks(const int* __restrict__ cnt, const int* __restrict__ boff,
                            int* __restrict__ rowptr, int n) {
    __shared__ int s[256];
    int b = blockIdx.x, t = threadIdx.x;
    int i = b * 256 + t;
    s[t] = i < n ? cnt[i] : 0;
    __syncthreads();
    for (int o = 1; o < 256; o <<= 1) {
        int u = t >= o ? s[t - o] : 0;
        __syncthreads();
        s[t] += u;
        __syncthreads();
    }
    if (i < n) rowptr[i + 1] = s[t] + boff[b];
    if (i == 0) rowptr[0] = 0;
}

__global__ void fill_csr(const int* __restrict__ src, const int* __restrict__ dst,
                         const float* __restrict__ ew, int* __restrict__ fillpos,
                         int* __restrict__ col, float* __restrict__ ewp,
                         int* __restrict__ eorig, int e) {
    int i = blockIdx.x * blockDim.x + threadIdx.x;
    if (i < e) {
        int d = dst[i];
        int p = atomicAdd(&fillpos[d], 1);
        col[p] = src[i];
        ewp[p] = ew[i];
        eorig[p] = i;
    }
}

// stable order: sort each row's slots by original edge index (insertion sort,
// deg ~ Poisson(16)) so per-row accumulation matches numpy's edge-order sums.
__global__ void sort_rows(const int* __restrict__ rowptr, int* __restrict__ col,
                          float* __restrict__ ewp, int* __restrict__ eorig, int n) {
    int i = blockIdx.x * blockDim.x + threadIdx.x;
    if (i >= n) return;
    int r0 = rowptr[i], r1 = rowptr[i + 1];
    for (int a = r0 + 1; a < r1; ++a) {
        int ke = eorig[a]; int kc = col[a]; float kw = ewp[a];
        int b = a - 1;
        while (b >= r0 && eorig[b] > ke) {
            eorig[b + 1] = eorig[b]; col[b + 1] = col[b]; ewp[b + 1] = ewp[b];
            --b;
        }
        eorig[b + 1] = ke; col[b + 1] = kc; ewp[b + 1] = kw;
    }
}

__global__ void deg_dinv(const int* __restrict__ rowptr, const float* __restrict__ ewp,
                         float* __restrict__ dinv, int n) {
    int i = blockIdx.x * blockDim.x + threadIdx.x;
    if (i < n) {
        float s = 0.0f;
        int r1 = rowptr[i + 1];
        for (int e = rowptr[i]; e < r1; ++e) s += ewp[e];
        dinv[i] = 1.0f / sqrtf(s + 1.0f);   // exact, matches np within 1 ulp
    }
}

__global__ void enorm_csr(const int* __restrict__ rowptr, const int* __restrict__ col,
                          const float* __restrict__ ewp, const float* __restrict__ dinv,
                          float* __restrict__ enormp, int n) {
    int i = blockIdx.x * blockDim.x + threadIdx.x;
    if (i < n) {
        float di = dinv[i];
        int r1 = rowptr[i + 1];
        for (int e = rowptr[i]; e < r1; ++e)
            enormp[e] = dinv[col[e]] * ewp[e] * di;
    }
}

// ---------------- register-tiled GEMM: out[n,64] = X[n,Kd] @ W[Kd,64] ----------
template<int Kd>
__global__ void __launch_bounds__(256) gemm_tile(const float* __restrict__ X,
                                                 const float* __restrict__ W,
                                                 float* __restrict__ out, int n) {
    __shared__ float sW[Kd * 64];
    const int tid = threadIdx.x;
    for (int t = tid; t < Kd * 16; t += 256)
        ((float4*)sW)[t] = ((const float4*)W)[t];
    __syncthreads();

    const int cq = tid >> 6;
    const int rg = tid & 63;
    const int row0 = blockIdx.x * 256 + rg * 4;
    const float4* sW4 = (const float4*)sW;

    float4 acc[4][4];
    #pragma unroll
    for (int r = 0; r < 4; ++r)
        #pragma unroll
        for (int c = 0; c < 4; ++c) acc[r][c] = make_float4(0.f, 0.f, 0.f, 0.f);

    int rl[4];
    #pragma unroll
    for (int r = 0; r < 4; ++r) {
        int rr = row0 + r;
        rl[r] = rr < n ? rr : (n - 1);
    }

    for (int k0 = 0; k0 < Kd; k0 += 8) {
        float4 xa[4][2];
        #pragma unroll
        for (int r = 0; r < 4; ++r) {
            const float4* xp = (const float4*)(X + (size_t)rl[r] * Kd + k0);
            xa[r][0] = xp[0];
            xa[r][1] = xp[1];
        }
        #pragma unroll
        for (int kk = 0; kk < 8; ++kk) {
            float xk[4];
            #pragma unroll
            for (int r = 0; r < 4; ++r) {
                float4 h = xa[r][kk >> 2];
                xk[r] = (kk & 3) == 0 ? h.x : (kk & 3) == 1 ? h.y : (kk & 3) == 2 ? h.z : h.w;
            }
            #pragma unroll
            for (int c = 0; c < 4; ++c) {
                float4 w4 = sW4[(k0 + kk) * 16 + cq * 4 + c];
                #pragma unroll
                for (int r = 0; r < 4; ++r) {
                    acc[r][c].x += xk[r] * w4.x;
                    acc[r][c].y += xk[r] * w4.y;
                    acc[r][c].z += xk[r] * w4.z;
                    acc[r][c].w += xk[r] * w4.w;
                }
            }
        }
    }

    #pragma unroll
    for (int r = 0; r < 4; ++r) {
        int rr = row0 + r;
        if (rr < n) {
            float4* op = (float4*)(out + (size_t)rr * 64 + cq * 16);
            #pragma unroll
            for (int c = 0; c < 4; ++c) op[c] = acc[r][c];
        }
    }
}

// -------- fused CSR aggregation (64 feats): one wave per dst row, lane = feat --------
__global__ void __launch_bounds__(256) agg64_fused(const int* __restrict__ rowptr,
                                                   const int* __restrict__ col,
                                                   const float* __restrict__ enormp,
                                                   const float* __restrict__ hpre,
                                                   const float* __restrict__ dinv,
                                                   const float* __restrict__ bias,
                                                   float* __restrict__ hout, int n) {
    int gid = blockIdx.x * 256 + threadIdx.x;
    int row = gid >> 6;
    int lane = gid & 63;
    if (row >= n) return;
    int r0 = rowptr[row], r1 = rowptr[row + 1];
    float acc = 0.0f;
    for (int base = r0; base < r1; base += 64) {
        int e = base + lane;
        int cv = 0; float ev = 0.0f;
        if (e < r1) { cv = col[e]; ev = enormp[e]; }
        int m = r1 - base; if (m > 64) m = 64;
        for (int j = 0; j < m; ++j) {
            int s = __shfl(cv, j, 64);
            float coef = __shfl(ev, j, 64);
            acc += coef * hpre[(size_t)s * 64 + lane];
        }
    }
    float dv = dinv[row];
    hout[gid] = tanhf(acc + dv * dv * hpre[(size_t)row * 64 + lane] + bias[lane]);
}

// ---------------- h2 @ W2 (64 -> 1), one wave per row ----------------
__global__ void gemv64(const float* __restrict__ h, const float* __restrict__ w,
                       float* __restrict__ out, int n) {
    int gid = blockIdx.x * blockDim.x + threadIdx.x;
    int row = gid >> 6;
    int lane = gid & 63;
    if (row >= n) return;
    float v = h[(size_t)row * 64 + lane] * w[lane];
    for (int off = 32; off > 0; off >>= 1) v += __shfl_down(v, off, 64);
    if (lane == 0) out[row] = v;
}

// -------- fused CSR aggregation (1 feat): one thread per dst row --------
__global__ void agg1_fused(const int* __restrict__ rowptr, const int* __restrict__ col,
                           const float* __restrict__ enormp, const float* __restrict__ hpre3,
                           const float* __restrict__ dinv, const float* __restrict__ b2,
                           float* __restrict__ h3, int n) {
    int i = blockIdx.x * blockDim.x + threadIdx.x;
    if (i >= n) return;
    float acc = 0.0f;
    int r1 = rowptr[i + 1];
    for (int e = rowptr[i]; e < r1; ++e) acc += enormp[e] * hpre3[col[e]];
    float dv = dinv[i];
    h3[i] = tanhf(acc + dv * dv * hpre3[i] + b2[0]);
}

// ---------------- group compaction ----------------
__global__ void compact_kernel(const int* __restrict__ group, int* cnt, int* lists, int n) {
    int i = blockIdx.x * blockDim.x + threadIdx.x;
    if (i < n) {
        int g = group[i];
        int p = atomicAdd(&cnt[g], 1);
        if (p < CAP) lists[g * CAP + p] = i;
    }
}

// ---------------- per-group top-K by h3 (desc, tie: lower index) ----------------
__global__ void __launch_bounds__(256) topk_kernel(const int* __restrict__ cnt,
                                                   const int* __restrict__ lists,
                                                   const float* __restrict__ h3,
                                                   int* __restrict__ topk) {
    __shared__ float sval[SORTN];
    __shared__ int   sidx[SORTN];
    int g = blockIdx.x;
    int tid = threadIdx.x;
    int c = cnt[g];
    if (c > CAP) c = CAP;
    for (int t = tid; t < SORTN; t += blockDim.x) {
        if (t < c) {
            int node = lists[g * CAP + t];
            sval[t] = h3[node];
            sidx[t] = node;
        } else {
            sval[t] = -INFINITY;
            sidx[t] = 0x7fffffff;
        }
    }
    for (int k = 2; k <= SORTN; k <<= 1) {
        for (int j = k >> 1; j > 0; j >>= 1) {
            __syncthreads();
            for (int t = tid; t < SORTN; t += blockDim.x) {
                int l = t ^ j;
                if (l > t) {
                    bool dirDesc = ((t & k) == 0);
                    float v0 = sval[t], v1 = sval[l];
                    int   i0 = sidx[t], i1 = sidx[l];
                    bool aBeforeB = (v0 > v1) || (v0 == v1 && i0 < i1);
                    bool doSwap = dirDesc ? !aBeforeB : aBeforeB;
                    if (doSwap) {
                        sval[t] = v1; sval[l] = v0;
                        sidx[t] = i1; sidx[l] = i0;
                    }
                }
            }
        }
    }
    __syncthreads();
    if (tid < KTOP) topk[g * KTOP + tid] = sidx[tid];
}

// ---------------- fused sort-pool gather + conv1 + maxpool + conv2 ----------------
__global__ void __launch_bounds__(256) pool_conv(const float* __restrict__ h1,
                                                 const float* __restrict__ h2,
                                                 const float* __restrict__ h3,
                                                 const int* __restrict__ topk,
                                                 const float* __restrict__ c1w,
                                                 const float* __restrict__ c1b,
                                                 const float* __restrict__ c2w,
                                                 const float* __restrict__ c2b,
                                                 float* __restrict__ out) {
    __shared__ float sfeat[KTOP * DFLAT];
    __shared__ float sy[NC1 * KTOP];
    __shared__ float sm[NC1 * (KTOP / 2)];
    int g = blockIdx.x;
    int tid = threadIdx.x;

    for (int t = tid; t < KTOP * DFLAT; t += blockDim.x) {
        int k = t / DFLAT, d = t - k * DFLAT;
        int node = topk[g * KTOP + k];
        float v;
        if (d < 64)        v = h1[(size_t)node * 64 + d];
        else if (d < 128)  v = h2[(size_t)node * 64 + (d - 64)];
        else               v = h3[node];
        sfeat[t] = v;
    }
    __syncthreads();

    for (int t = tid; t < NC1 * KTOP; t += blockDim.x) {
        int c = t / KTOP, k = t - c * KTOP;
        float acc = c1b[c];
        const float* w = c1w + c * DFLAT;
        const float* f = sfeat + k * DFLAT;
        for (int d = 0; d < DFLAT; ++d) acc += f[d] * w[d];
        sy[c * KTOP + k] = fmaxf(acc, 0.0f);
    }
    __syncthreads();

    for (int t = tid; t < NC1 * (KTOP / 2); t += blockDim.x) {
        int c = t / (KTOP / 2), j = t - c * (KTOP / 2);
        sm[t] = fmaxf(sy[c * KTOP + 2 * j], sy[c * KTOP + 2 * j + 1]);
    }
    __syncthreads();

    for (int t = tid; t < NC2 * TOUT; t += blockDim.x) {
        int c2 = t / TOUT, tt = t - c2 * TOUT;
        float acc = c2b[c2];
        for (int c1i = 0; c1i < NC1; ++c1i) {
            const float* w = c2w + (c2 * NC1 + c1i) * KSZ;
            const float* m = sm + c1i * (KTOP / 2) + tt;
            for (int s = 0; s < KSZ; ++s) acc += m[s] * w[s];
        }
        out[g * NC2 * TOUT + t] += fmaxf(acc, 0.0f);
    }
}

// ---------------- host ----------------
static inline size_t align256(size_t x) { return (x + 255) & ~(size_t)255; }

extern "C" void kernel_launch(void* const* d_in, const int* in_sizes, int n_in,
                              void* d_out, int out_size, void* d_ws, size_t ws_size,
                              hipStream_t stream) {
    const float* x       = (const float*)d_in[0];
    const int*   eidx    = (const int*)d_in[1];    // [R,2,E]
    const float* ew      = (const float*)d_in[2];  // [R,E]
    const int*   group   = (const int*)d_in[3];    // [N]
    const float* W0      = (const float*)d_in[4];  // [R,128,64]
    const float* b0      = (const float*)d_in[5];
    const float* W1      = (const float*)d_in[6];  // [R,64,64]
    const float* b1      = (const float*)d_in[7];
    const float* W2      = (const float*)d_in[8];  // [R,64,1]
    const float* b2      = (const float*)d_in[9];
    const float* c1w     = (const float*)d_in[10];
    const float* c1b     = (const float*)d_in[11];
    const float* c2w     = (const float*)d_in[12];
    const float* c2b     = (const float*)d_in[13];
    float* out = (float*)d_out;

    char* ws = (char*)d_ws;
    size_t off = 0;
    float* dinv    = (float*)(ws + off); off = align256(off + (size_t)N_NODES * 4);
    int*   rowptr  = (int*)(ws + off);   off = align256(off + (size_t)(N_NODES + 1) * 4);
    int*   fillpos = (int*)(ws + off);   off = align256(off + (size_t)N_NODES * 4);
    int*   ccnt    = (int*)(ws + off);   off = align256(off + (size_t)N_NODES * 4);
    int*   bsum    = (int*)(ws + off);   off = align256(off + (size_t)512 * 4);
    int*   col     = (int*)(ws + off);   off = align256(off + (size_t)E_EDGES * 4);
    float* ewp     = (float*)(ws + off); off = align256(off + (size_t)E_EDGES * 4);
    int*   eorig   = (int*)(ws + off);   off = align256(off + (size_t)E_EDGES * 4);
    float* enormp  = (float*)(ws + off); off = align256(off + (size_t)E_EDGES * 4);
    float* hpre    = (float*)(ws + off); off = align256(off + (size_t)N_NODES * 64 * 4);
    float* h1      = (float*)(ws + off); off = align256(off + (size_t)N_NODES * 64 * 4);
    float* h2      = (float*)(ws + off); off = align256(off + (size_t)N_NODES * 64 * 4);
    float* hpre3   = (float*)(ws + off); off = align256(off + (size_t)N_NODES * 4);
    float* h3      = (float*)(ws + off); off = align256(off + (size_t)N_NODES * 4);
    int*   cnt     = (int*)(ws + off);   off = align256(off + (size_t)NG * 4);
    int*   lists   = (int*)(ws + off);   off = align256(off + (size_t)NG * CAP * 4);
    int*   topk    = (int*)(ws + off);   off = align256(off + (size_t)NG * KTOP * 4);
    (void)ws_size;

    const int B = 256;
    const int nOut = NG * NC2 * TOUT;
    const int gN   = (N_NODES + B - 1) / B;           // 391
    const int gE   = (E_EDGES + B - 1) / B;           // 6250
    const int gW   = (N_NODES * 64 + B - 1) / B;      // 25000
    const int gT   = (N_NODES + 255) / 256;           // gemm_tile

    zero_f32<<<(nOut + B - 1) / B, B, 0, stream>>>(out, nOut);

    // group compaction is relation-invariant — do once
    zero_i32<<<1, B, 0, stream>>>(cnt, NG);
    compact_kernel<<<gN, B, 0, stream>>>(group, cnt, lists, N_NODES);

    for (int r = 0; r < R_REL; ++r) {
        const int* src = eidx + (size_t)r * 2 * E_EDGES;
        const int* dst = src + E_EDGES;
        const float* ewr = ew + (size_t)r * E_EDGES;

        // ---- CSR build (stable in original edge order) ----
        zero_i32<<<gN, B, 0, stream>>>(ccnt, N_NODES);
        hist_kernel<<<gE, B, 0, stream>>>(dst, ccnt, E_EDGES);
        block_sum<<<gN, B, 0, stream>>>(ccnt, bsum, N_NODES);
        scan_bsum<<<1, 512, 0, stream>>>(bsum, gN);
        scan_blocks<<<gN, B, 0, stream>>>(ccnt, bsum, rowptr, N_NODES);
        copy_i32<<<gN, B, 0, stream>>>(rowptr, fillpos, N_NODES);
        fill_csr<<<gE, B, 0, stream>>>(src, dst, ewr, fillpos, col, ewp, eorig, E_EDGES);
        sort_rows<<<gN, B, 0, stream>>>(rowptr, col, ewp, eorig, N_NODES);
        deg_dinv<<<gN, B, 0, stream>>>(rowptr, ewp, dinv, N_NODES);
        enorm_csr<<<gN, B, 0, stream>>>(rowptr, col, ewp, dinv, enormp, N_NODES);

        // layer 1
        gemm_tile<128><<<gT, B, 0, stream>>>(x, W0 + (size_t)r * 128 * 64, hpre, N_NODES);
        agg64_fused<<<gW, B, 0, stream>>>(rowptr, col, enormp, hpre, dinv,
                                          b0 + (size_t)r * 64, h1, N_NODES);
        // layer 2
        gemm_tile<64><<<gT, B, 0, stream>>>(h1, W1 + (size_t)r * 64 * 64, hpre, N_NODES);
        agg64_fused<<<gW, B, 0, stream>>>(rowptr, col, enormp, hpre, dinv,
                                          b1 + (size_t)r * 64, h2, N_NODES);
        // layer 3
        gemv64<<<gW, B, 0, stream>>>(h2, W2 + (size_t)r * 64, hpre3, N_NODES);
        agg1_fused<<<gN, B, 0, stream>>>(rowptr, col, enormp, hpre3, dinv, b2 + r, h3, N_NODES);

        // sort pooling + convs
        topk_kernel<<<NG, B, 0, stream>>>(cnt, lists, h3, topk);
        pool_conv<<<NG, B, 0, stream>>>(h1, h2, h3, topk, c1w, c1b, c2w, c2b, out);
    }
}

// Round 5
// 2236.363 us; speedup vs baseline: 2.4189x; 1.1979x over previous
//
#include <hip/hip_runtime.h>
#include <math.h>

#define N_NODES 100000
#define R_REL   3
#define E_EDGES 1600000
#define HID     64
#define DFLAT   129
#define KTOP    30
#define NC1     16
#define NC2     32
#define KSZ     5
#define NG      64
#define CAP     2048
#define SLOTS   8     // CAP / 256
#define TOUT    11    // K/2 - KS + 1

// ---------------- utility ----------------
__global__ void zero_f32(float* p, int n) {
    int i = blockIdx.x * blockDim.x + threadIdx.x;
    int stride = gridDim.x * blockDim.x;
    for (; i < n; i += stride) p[i] = 0.0f;
}

__global__ void zero_i32(int* p, int n) {
    int i = blockIdx.x * blockDim.x + threadIdx.x;
    if (i < n) p[i] = 0;
}

__global__ void copy_i32(const int* a, int* b, int n) {
    int i = blockIdx.x * blockDim.x + threadIdx.x;
    if (i < n) b[i] = a[i];
}

// ---------------- CSR build ----------------
__global__ void hist_kernel(const int* __restrict__ dst, int* __restrict__ cnt, int e) {
    int i = blockIdx.x * blockDim.x + threadIdx.x;
    if (i < e) atomicAdd(&cnt[dst[i]], 1);
}

__global__ void block_sum(const int* __restrict__ cnt, int* __restrict__ bsum, int n) {
    __shared__ int s[256];
    int i = blockIdx.x * 256 + threadIdx.x;
    s[threadIdx.x] = i < n ? cnt[i] : 0;
    __syncthreads();
    for (int o = 128; o > 0; o >>= 1) {
        if (threadIdx.x < o) s[threadIdx.x] += s[threadIdx.x + o];
        __syncthreads();
    }
    if (threadIdx.x == 0) bsum[blockIdx.x] = s[0];
}

__global__ void __launch_bounds__(512) scan_bsum(int* bsum, int nb) {
    __shared__ int s[512];
    int t = threadIdx.x;
    int orig = t < nb ? bsum[t] : 0;
    s[t] = orig;
    __syncthreads();
    for (int o = 1; o < 512; o <<= 1) {
        int v = t >= o ? s[t - o] : 0;
        __syncthreads();
        s[t] += v;
        __syncthreads();
    }
    if (t < nb) bsum[t] = s[t] - orig;   // exclusive
}

__global__ void scan_blocks(const int* __restrict__ cnt, const int* __restrict__ boff,
                            int* __restrict__ rowptr, int n) {
    __shared__ int s[256];
    int b = blockIdx.x, t = threadIdx.x;
    int i = b * 256 + t;
    s[t] = i < n ? cnt[i] : 0;
    __syncthreads();
    for (int o = 1; o < 256; o <<= 1) {
        int u = t >= o ? s[t - o] : 0;
        __syncthreads();
        s[t] += u;
        __syncthreads();
    }
    if (i < n) rowptr[i + 1] = s[t] + boff[b];
    if (i == 0) rowptr[0] = 0;
}

__global__ void fill_csr(const int* __restrict__ src, const int* __restrict__ dst,
                         const float* __restrict__ ew, int* __restrict__ fillpos,
                         int* __restrict__ col, float* __restrict__ ewp,
                         int* __restrict__ eorig, int e) {
    int i = blockIdx.x * blockDim.x + threadIdx.x;
    if (i < e) {
        int d = dst[i];
        int p = atomicAdd(&fillpos[d], 1);
        col[p] = src[i];
        ewp[p] = ew[i];
        eorig[p] = i;
    }
}

// stable order: sort each row's slots by original edge index so per-row
// accumulation matches numpy's edge-order sums (keeps top-k selection stable).
__global__ void sort_rows(const int* __restrict__ rowptr, int* __restrict__ col,
                          float* __restrict__ ewp, int* __restrict__ eorig, int n) {
    int i = blockIdx.x * blockDim.x + threadIdx.x;
    if (i >= n) return;
    int r0 = rowptr[i], r1 = rowptr[i + 1];
    for (int a = r0 + 1; a < r1; ++a) {
        int ke = eorig[a]; int kc = col[a]; float kw = ewp[a];
        int b = a - 1;
        while (b >= r0 && eorig[b] > ke) {
            eorig[b + 1] = eorig[b]; col[b + 1] = col[b]; ewp[b + 1] = ewp[b];
            --b;
        }
        eorig[b + 1] = ke; col[b + 1] = kc; ewp[b + 1] = kw;
    }
}

__global__ void deg_dinv(const int* __restrict__ rowptr, const float* __restrict__ ewp,
                         float* __restrict__ dinv, int n) {
    int i = blockIdx.x * blockDim.x + threadIdx.x;
    if (i < n) {
        float s = 0.0f;
        int r1 = rowptr[i + 1];
        for (int e = rowptr[i]; e < r1; ++e) s += ewp[e];
        dinv[i] = 1.0f / sqrtf(s + 1.0f);
    }
}

__global__ void enorm_csr(const int* __restrict__ rowptr, const int* __restrict__ col,
                          const float* __restrict__ ewp, const float* __restrict__ dinv,
                          float* __restrict__ enormp, int n) {
    int i = blockIdx.x * blockDim.x + threadIdx.x;
    if (i < n) {
        float di = dinv[i];
        int r1 = rowptr[i + 1];
        for (int e = rowptr[i]; e < r1; ++e)
            enormp[e] = dinv[col[e]] * ewp[e] * di;
    }
}

// ---------------- register-tiled GEMM: out[n,64] = X[n,Kd] @ W[Kd,64] ----------
template<int Kd>
__global__ void __launch_bounds__(256) gemm_tile(const float* __restrict__ X,
                                                 const float* __restrict__ W,
                                                 float* __restrict__ out, int n) {
    __shared__ float sW[Kd * 64];
    const int tid = threadIdx.x;
    for (int t = tid; t < Kd * 16; t += 256)
        ((float4*)sW)[t] = ((const float4*)W)[t];
    __syncthreads();

    const int cq = tid >> 6;
    const int rg = tid & 63;
    const int row0 = blockIdx.x * 256 + rg * 4;
    const float4* sW4 = (const float4*)sW;

    float4 acc[4][4];
    #pragma unroll
    for (int r = 0; r < 4; ++r)
        #pragma unroll
        for (int c = 0; c < 4; ++c) acc[r][c] = make_float4(0.f, 0.f, 0.f, 0.f);

    int rl[4];
    #pragma unroll
    for (int r = 0; r < 4; ++r) {
        int rr = row0 + r;
        rl[r] = rr < n ? rr : (n - 1);
    }

    for (int k0 = 0; k0 < Kd; k0 += 8) {
        float4 xa[4][2];
        #pragma unroll
        for (int r = 0; r < 4; ++r) {
            const float4* xp = (const float4*)(X + (size_t)rl[r] * Kd + k0);
            xa[r][0] = xp[0];
            xa[r][1] = xp[1];
        }
        #pragma unroll
        for (int kk = 0; kk < 8; ++kk) {
            float xk[4];
            #pragma unroll
            for (int r = 0; r < 4; ++r) {
                float4 h = xa[r][kk >> 2];
                xk[r] = (kk & 3) == 0 ? h.x : (kk & 3) == 1 ? h.y : (kk & 3) == 2 ? h.z : h.w;
            }
            #pragma unroll
            for (int c = 0; c < 4; ++c) {
                float4 w4 = sW4[(k0 + kk) * 16 + cq * 4 + c];
                #pragma unroll
                for (int r = 0; r < 4; ++r) {
                    acc[r][c].x += xk[r] * w4.x;
                    acc[r][c].y += xk[r] * w4.y;
                    acc[r][c].z += xk[r] * w4.z;
                    acc[r][c].w += xk[r] * w4.w;
                }
            }
        }
    }

    #pragma unroll
    for (int r = 0; r < 4; ++r) {
        int rr = row0 + r;
        if (rr < n) {
            float4* op = (float4*)(out + (size_t)rr * 64 + cq * 16);
            #pragma unroll
            for (int c = 0; c < 4; ++c) op[c] = acc[r][c];
        }
    }
}

// -------- fused CSR aggregation (64 feats): one wave per dst row, lane = feat --------
__global__ void __launch_bounds__(256) agg64_fused(const int* __restrict__ rowptr,
                                                   const int* __restrict__ col,
                                                   const float* __restrict__ enormp,
                                                   const float* __restrict__ hpre,
                                                   const float* __restrict__ dinv,
                                                   const float* __restrict__ bias,
                                                   float* __restrict__ hout, int n) {
    int gid = blockIdx.x * 256 + threadIdx.x;
    int row = gid >> 6;
    int lane = gid & 63;
    if (row >= n) return;
    int r0 = rowptr[row], r1 = rowptr[row + 1];
    float acc = 0.0f;
    for (int base = r0; base < r1; base += 64) {
        int e = base + lane;
        int cv = 0; float ev = 0.0f;
        if (e < r1) { cv = col[e]; ev = enormp[e]; }
        int m = r1 - base; if (m > 64) m = 64;
        for (int j = 0; j < m; ++j) {
            int s = __shfl(cv, j, 64);
            float coef = __shfl(ev, j, 64);
            acc += coef * hpre[(size_t)s * 64 + lane];
        }
    }
    float dv = dinv[row];
    hout[gid] = tanhf(acc + dv * dv * hpre[(size_t)row * 64 + lane] + bias[lane]);
}

// ---------------- h2 @ W2 (64 -> 1), one wave per row ----------------
__global__ void gemv64(const float* __restrict__ h, const float* __restrict__ w,
                       float* __restrict__ out, int n) {
    int gid = blockIdx.x * blockDim.x + threadIdx.x;
    int row = gid >> 6;
    int lane = gid & 63;
    if (row >= n) return;
    float v = h[(size_t)row * 64 + lane] * w[lane];
    for (int off = 32; off > 0; off >>= 1) v += __shfl_down(v, off, 64);
    if (lane == 0) out[row] = v;
}

// -------- fused CSR aggregation (1 feat): one thread per dst row --------
__global__ void agg1_fused(const int* __restrict__ rowptr, const int* __restrict__ col,
                           const float* __restrict__ enormp, const float* __restrict__ hpre3,
                           const float* __restrict__ dinv, const float* __restrict__ b2,
                           float* __restrict__ h3, int n) {
    int i = blockIdx.x * blockDim.x + threadIdx.x;
    if (i >= n) return;
    float acc = 0.0f;
    int r1 = rowptr[i + 1];
    for (int e = rowptr[i]; e < r1; ++e) acc += enormp[e] * hpre3[col[e]];
    float dv = dinv[i];
    h3[i] = tanhf(acc + dv * dv * hpre3[i] + b2[0]);
}

// ---------------- group compaction ----------------
__global__ void compact_kernel(const int* __restrict__ group, int* cnt, int* lists, int n) {
    int i = blockIdx.x * blockDim.x + threadIdx.x;
    if (i < n) {
        int g = group[i];
        int p = atomicAdd(&cnt[g], 1);
        if (p < CAP) lists[g * CAP + p] = i;
    }
}

// ---------------- per-group top-K by h3: iterative selection in registers ----------
// key = (monotone_float_bits(h3) << 32) | ~node  — value desc, index asc; unique.
__device__ __forceinline__ unsigned int fkey(float v) {
    unsigned int b = __float_as_uint(v);
    return (b & 0x80000000u) ? ~b : (b | 0x80000000u);
}

__global__ void __launch_bounds__(256) topk_kernel(const int* __restrict__ cnt,
                                                   const int* __restrict__ lists,
                                                   const float* __restrict__ h3,
                                                   int* __restrict__ topk) {
    __shared__ unsigned long long wmax[4];
    __shared__ unsigned long long winner;
    int g = blockIdx.x;
    int tid = threadIdx.x;
    int lane = tid & 63, wid = tid >> 6;
    int c = cnt[g];
    if (c > CAP) c = CAP;

    unsigned long long key[SLOTS];
    #pragma unroll
    for (int s = 0; s < SLOTS; ++s) {
        int e = s * 256 + tid;
        if (e < c) {
            int node = lists[g * CAP + e];
            key[s] = ((unsigned long long)fkey(h3[node]) << 32) | (unsigned int)(~node);
        } else {
            key[s] = 0ull;
        }
    }

    for (int k = 0; k < KTOP; ++k) {
        unsigned long long best = 0ull;
        #pragma unroll
        for (int s = 0; s < SLOTS; ++s) best = key[s] > best ? key[s] : best;
        #pragma unroll
        for (int off = 32; off > 0; off >>= 1) {
            unsigned long long o = __shfl_down(best, off, 64);
            best = o > best ? o : best;
        }
        if (lane == 0) wmax[wid] = best;
        __syncthreads();
        if (tid == 0) {
            unsigned long long b = wmax[0];
            for (int w = 1; w < 4; ++w) b = wmax[w] > b ? wmax[w] : b;
            winner = b;
            topk[g * KTOP + k] = ~(int)(unsigned int)b;
        }
        __syncthreads();
        unsigned long long w = winner;
        #pragma unroll
        for (int s = 0; s < SLOTS; ++s) if (key[s] == w) key[s] = 0ull;
        __syncthreads();
    }
}

// ---------------- fused sort-pool gather + conv1 + maxpool + conv2 ----------------
__global__ void __launch_bounds__(256) pool_conv(const float* __restrict__ h1,
                                                 const float* __restrict__ h2,
                                                 const float* __restrict__ h3,
                                                 const int* __restrict__ topk,
                                                 const float* __restrict__ c1w,
                                                 const float* __restrict__ c1b,
                                                 const float* __restrict__ c2w,
                                                 const float* __restrict__ c2b,
                                                 float* __restrict__ out) {
    __shared__ float sfeat[KTOP * DFLAT];
    __shared__ float sy[NC1 * KTOP];
    __shared__ float sm[NC1 * (KTOP / 2)];
    int g = blockIdx.x;
    int tid = threadIdx.x;

    for (int t = tid; t < KTOP * DFLAT; t += blockDim.x) {
        int k = t / DFLAT, d = t - k * DFLAT;
        int node = topk[g * KTOP + k];
        float v;
        if (d < 64)        v = h1[(size_t)node * 64 + d];
        else if (d < 128)  v = h2[(size_t)node * 64 + (d - 64)];
        else               v = h3[node];
        sfeat[t] = v;
    }
    __syncthreads();

    for (int t = tid; t < NC1 * KTOP; t += blockDim.x) {
        int c = t / KTOP, k = t - c * KTOP;
        float acc = c1b[c];
        const float* w = c1w + c * DFLAT;
        const float* f = sfeat + k * DFLAT;
        for (int d = 0; d < DFLAT; ++d) acc += f[d] * w[d];
        sy[c * KTOP + k] = fmaxf(acc, 0.0f);
    }
    __syncthreads();

    for (int t = tid; t < NC1 * (KTOP / 2); t += blockDim.x) {
        int c = t / (KTOP / 2), j = t - c * (KTOP / 2);
        sm[t] = fmaxf(sy[c * KTOP + 2 * j], sy[c * KTOP + 2 * j + 1]);
    }
    __syncthreads();

    for (int t = tid; t < NC2 * TOUT; t += blockDim.x) {
        int c2 = t / TOUT, tt = t - c2 * TOUT;
        float acc = c2b[c2];
        for (int c1i = 0; c1i < NC1; ++c1i) {
            const float* w = c2w + (c2 * NC1 + c1i) * KSZ;
            const float* m = sm + c1i * (KTOP / 2) + tt;
            for (int s = 0; s < KSZ; ++s) acc += m[s] * w[s];
        }
        out[g * NC2 * TOUT + t] += fmaxf(acc, 0.0f);
    }
}

// ---------------- host ----------------
static inline size_t align256(size_t x) { return (x + 255) & ~(size_t)255; }

extern "C" void kernel_launch(void* const* d_in, const int* in_sizes, int n_in,
                              void* d_out, int out_size, void* d_ws, size_t ws_size,
                              hipStream_t stream) {
    const float* x       = (const float*)d_in[0];
    const int*   eidx    = (const int*)d_in[1];    // [R,2,E]
    const float* ew      = (const float*)d_in[2];  // [R,E]
    const int*   group   = (const int*)d_in[3];    // [N]
    const float* W0      = (const float*)d_in[4];  // [R,128,64]
    const float* b0      = (const float*)d_in[5];
    const float* W1      = (const float*)d_in[6];  // [R,64,64]
    const float* b1      = (const float*)d_in[7];
    const float* W2      = (const float*)d_in[8];  // [R,64,1]
    const float* b2      = (const float*)d_in[9];
    const float* c1w     = (const float*)d_in[10];
    const float* c1b     = (const float*)d_in[11];
    const float* c2w     = (const float*)d_in[12];
    const float* c2b     = (const float*)d_in[13];
    float* out = (float*)d_out;

    char* ws = (char*)d_ws;
    size_t off = 0;
    float* dinv    = (float*)(ws + off); off = align256(off + (size_t)N_NODES * 4);
    int*   rowptr  = (int*)(ws + off);   off = align256(off + (size_t)(N_NODES + 1) * 4);
    int*   fillpos = (int*)(ws + off);   off = align256(off + (size_t)N_NODES * 4);
    int*   ccnt    = (int*)(ws + off);   off = align256(off + (size_t)N_NODES * 4);
    int*   bsum    = (int*)(ws + off);   off = align256(off + (size_t)512 * 4);
    int*   col     = (int*)(ws + off);   off = align256(off + (size_t)E_EDGES * 4);
    float* ewp     = (float*)(ws + off); off = align256(off + (size_t)E_EDGES * 4);
    int*   eorig   = (int*)(ws + off);   off = align256(off + (size_t)E_EDGES * 4);
    float* enormp  = (float*)(ws + off); off = align256(off + (size_t)E_EDGES * 4);
    float* hpre    = (float*)(ws + off); off = align256(off + (size_t)N_NODES * 64 * 4);
    float* h1      = (float*)(ws + off); off = align256(off + (size_t)N_NODES * 64 * 4);
    float* h2      = (float*)(ws + off); off = align256(off + (size_t)N_NODES * 64 * 4);
    float* hpre3   = (float*)(ws + off); off = align256(off + (size_t)N_NODES * 4);
    float* h3      = (float*)(ws + off); off = align256(off + (size_t)N_NODES * 4);
    int*   cnt     = (int*)(ws + off);   off = align256(off + (size_t)NG * 4);
    int*   lists   = (int*)(ws + off);   off = align256(off + (size_t)NG * CAP * 4);
    int*   topk    = (int*)(ws + off);   off = align256(off + (size_t)NG * KTOP * 4);
    (void)ws_size;

    const int B = 256;
    const int nOut = NG * NC2 * TOUT;
    const int gN   = (N_NODES + B - 1) / B;           // 391
    const int gE   = (E_EDGES + B - 1) / B;           // 6250
    const int gW   = (N_NODES * 64 + B - 1) / B;      // 25000
    const int gT   = (N_NODES + 255) / 256;           // gemm_tile

    zero_f32<<<(nOut + B - 1) / B, B, 0, stream>>>(out, nOut);

    // group compaction is relation-invariant — do once
    zero_i32<<<1, B, 0, stream>>>(cnt, NG);
    compact_kernel<<<gN, B, 0, stream>>>(group, cnt, lists, N_NODES);

    for (int r = 0; r < R_REL; ++r) {
        const int* src = eidx + (size_t)r * 2 * E_EDGES;
        const int* dst = src + E_EDGES;
        const float* ewr = ew + (size_t)r * E_EDGES;

        // ---- CSR build (stable in original edge order) ----
        zero_i32<<<gN, B, 0, stream>>>(ccnt, N_NODES);
        hist_kernel<<<gE, B, 0, stream>>>(dst, ccnt, E_EDGES);
        block_sum<<<gN, B, 0, stream>>>(ccnt, bsum, N_NODES);
        scan_bsum<<<1, 512, 0, stream>>>(bsum, gN);
        scan_blocks<<<gN, B, 0, stream>>>(ccnt, bsum, rowptr, N_NODES);
        copy_i32<<<gN, B, 0, stream>>>(rowptr, fillpos, N_NODES);
        fill_csr<<<gE, B, 0, stream>>>(src, dst, ewr, fillpos, col, ewp, eorig, E_EDGES);
        sort_rows<<<gN, B, 0, stream>>>(rowptr, col, ewp, eorig, N_NODES);
        deg_dinv<<<gN, B, 0, stream>>>(rowptr, ewp, dinv, N_NODES);
        enorm_csr<<<gN, B, 0, stream>>>(rowptr, col, ewp, dinv, enormp, N_NODES);

        // layer 1
        gemm_tile<128><<<gT, B, 0, stream>>>(x, W0 + (size_t)r * 128 * 64, hpre, N_NODES);
        agg64_fused<<<gW, B, 0, stream>>>(rowptr, col, enormp, hpre, dinv,
                                          b0 + (size_t)r * 64, h1, N_NODES);
        // layer 2
        gemm_tile<64><<<gT, B, 0, stream>>>(h1, W1 + (size_t)r * 64 * 64, hpre, N_NODES);
        agg64_fused<<<gW, B, 0, stream>>>(rowptr, col, enormp, hpre, dinv,
                                          b1 + (size_t)r * 64, h2, N_NODES);
        // layer 3
        gemv64<<<gW, B, 0, stream>>>(h2, W2 + (size_t)r * 64, hpre3, N_NODES);
        agg1_fused<<<gN, B, 0, stream>>>(rowptr, col, enormp, hpre3, dinv, b2 + r, h3, N_NODES);

        // sort pooling + convs
        topk_kernel<<<NG, B, 0, stream>>>(cnt, lists, h3, topk);
        pool_conv<<<NG, B, 0, stream>>>(h1, h2, h3, topk, c1w, c1b, c2w, c2b, out);
    }
}

// Round 6
// 1837.097 us; speedup vs baseline: 2.9446x; 1.2173x over previous
//
#include <hip/hip_runtime.h>
#include <math.h>

#define N_NODES 100000
#define R_REL   3
#define E_EDGES 1600000
#define HID     64
#define DFLAT   129
#define KTOP    30
#define NC1     16
#define NC2     32
#define KSZ     5
#define NG      64
#define CAP     2048
#define SLOTS   8     // CAP / 256
#define TOUT    11    // K/2 - KS + 1
#define NBLK    391   // ceil(N_NODES/256)

// ---------------- utility ----------------
__global__ void zero_f32(float* p, int n) {
    int i = blockIdx.x * blockDim.x + threadIdx.x;
    int stride = gridDim.x * blockDim.x;
    for (; i < n; i += stride) p[i] = 0.0f;
}

__global__ void zero_i32(int* p, int n) {
    int i = blockIdx.x * blockDim.x + threadIdx.x;
    if (i < n) p[i] = 0;
}

__global__ void copy_i32(const int* a, int* b, int n) {
    int i = blockIdx.x * blockDim.x + threadIdx.x;
    if (i < n) b[i] = a[i];
}

// ---------------- CSR build ----------------
__global__ void hist_kernel(const int* __restrict__ dst, int* __restrict__ cnt, int e) {
    int i = blockIdx.x * blockDim.x + threadIdx.x;
    if (i < e) atomicAdd(&cnt[dst[i]], 1);
}

__global__ void block_sum(const int* __restrict__ cnt, int* __restrict__ bsum, int n) {
    __shared__ int s[256];
    int i = blockIdx.x * 256 + threadIdx.x;
    s[threadIdx.x] = i < n ? cnt[i] : 0;
    __syncthreads();
    for (int o = 128; o > 0; o >>= 1) {
        if (threadIdx.x < o) s[threadIdx.x] += s[threadIdx.x + o];
        __syncthreads();
    }
    if (threadIdx.x == 0) bsum[blockIdx.x] = s[0];
}

__global__ void __launch_bounds__(512) scan_bsum(int* bsum, int nb) {
    __shared__ int s[512];
    int t = threadIdx.x;
    int orig = t < nb ? bsum[t] : 0;
    s[t] = orig;
    __syncthreads();
    for (int o = 1; o < 512; o <<= 1) {
        int v = t >= o ? s[t - o] : 0;
        __syncthreads();
        s[t] += v;
        __syncthreads();
    }
    if (t < nb) bsum[t] = s[t] - orig;   // exclusive
}

__global__ void scan_blocks(const int* __restrict__ cnt, const int* __restrict__ boff,
                            int* __restrict__ rowptr, int n) {
    __shared__ int s[256];
    int b = blockIdx.x, t = threadIdx.x;
    int i = b * 256 + t;
    s[t] = i < n ? cnt[i] : 0;
    __syncthreads();
    for (int o = 1; o < 256; o <<= 1) {
        int u = t >= o ? s[t - o] : 0;
        __syncthreads();
        s[t] += u;
        __syncthreads();
    }
    if (i < n) rowptr[i + 1] = s[t] + boff[b];
    if (i == 0) rowptr[0] = 0;
}

__global__ void fill_csr(const int* __restrict__ src, const int* __restrict__ dst,
                         const float* __restrict__ ew, int* __restrict__ fillpos,
                         int* __restrict__ col, float* __restrict__ ewp,
                         int* __restrict__ eorig, int e) {
    int i = blockIdx.x * blockDim.x + threadIdx.x;
    if (i < e) {
        int d = dst[i];
        int p = atomicAdd(&fillpos[d], 1);
        col[p] = src[i];
        ewp[p] = ew[i];
        eorig[p] = i;
    }
}

// stable order: sort each row's slots by original edge index so per-row
// accumulation matches numpy's edge-order sums (keeps top-k selection stable).
__global__ void sort_rows(const int* __restrict__ rowptr, int* __restrict__ col,
                          float* __restrict__ ewp, int* __restrict__ eorig, int n) {
    int i = blockIdx.x * blockDim.x + threadIdx.x;
    if (i >= n) return;
    int r0 = rowptr[i], r1 = rowptr[i + 1];
    for (int a = r0 + 1; a < r1; ++a) {
        int ke = eorig[a]; int kc = col[a]; float kw = ewp[a];
        int b = a - 1;
        while (b >= r0 && eorig[b] > ke) {
            eorig[b + 1] = eorig[b]; col[b + 1] = col[b]; ewp[b + 1] = ewp[b];
            --b;
        }
        eorig[b + 1] = ke; col[b + 1] = kc; ewp[b + 1] = kw;
    }
}

__global__ void deg_dinv(const int* __restrict__ rowptr, const float* __restrict__ ewp,
                         float* __restrict__ dinv, int n) {
    int i = blockIdx.x * blockDim.x + threadIdx.x;
    if (i < n) {
        float s = 0.0f;
        int r1 = rowptr[i + 1];
        for (int e = rowptr[i]; e < r1; ++e) s += ewp[e];
        dinv[i] = 1.0f / sqrtf(s + 1.0f);
    }
}

__global__ void enorm_csr(const int* __restrict__ rowptr, const int* __restrict__ col,
                          const float* __restrict__ ewp, const float* __restrict__ dinv,
                          float* __restrict__ enormp, int n) {
    int i = blockIdx.x * blockDim.x + threadIdx.x;
    if (i < n) {
        float di = dinv[i];
        int r1 = rowptr[i + 1];
        for (int e = rowptr[i]; e < r1; ++e)
            enormp[e] = dinv[col[e]] * ewp[e] * di;
    }
}

// ---------------- register-tiled GEMM: out[n,64] = X[n,Kd] @ W[Kd,64] ----------
template<int Kd>
__global__ void __launch_bounds__(256) gemm_tile(const float* __restrict__ X,
                                                 const float* __restrict__ W,
                                                 float* __restrict__ out, int n) {
    __shared__ float sW[Kd * 64];
    const int tid = threadIdx.x;
    for (int t = tid; t < Kd * 16; t += 256)
        ((float4*)sW)[t] = ((const float4*)W)[t];
    __syncthreads();

    const int cq = tid >> 6;
    const int rg = tid & 63;
    const int row0 = blockIdx.x * 256 + rg * 4;
    const float4* sW4 = (const float4*)sW;

    float4 acc[4][4];
    #pragma unroll
    for (int r = 0; r < 4; ++r)
        #pragma unroll
        for (int c = 0; c < 4; ++c) acc[r][c] = make_float4(0.f, 0.f, 0.f, 0.f);

    int rl[4];
    #pragma unroll
    for (int r = 0; r < 4; ++r) {
        int rr = row0 + r;
        rl[r] = rr < n ? rr : (n - 1);
    }

    for (int k0 = 0; k0 < Kd; k0 += 8) {
        float4 xa[4][2];
        #pragma unroll
        for (int r = 0; r < 4; ++r) {
            const float4* xp = (const float4*)(X + (size_t)rl[r] * Kd + k0);
            xa[r][0] = xp[0];
            xa[r][1] = xp[1];
        }
        #pragma unroll
        for (int kk = 0; kk < 8; ++kk) {
            float xk[4];
            #pragma unroll
            for (int r = 0; r < 4; ++r) {
                float4 h = xa[r][kk >> 2];
                xk[r] = (kk & 3) == 0 ? h.x : (kk & 3) == 1 ? h.y : (kk & 3) == 2 ? h.z : h.w;
            }
            #pragma unroll
            for (int c = 0; c < 4; ++c) {
                float4 w4 = sW4[(k0 + kk) * 16 + cq * 4 + c];
                #pragma unroll
                for (int r = 0; r < 4; ++r) {
                    acc[r][c].x += xk[r] * w4.x;
                    acc[r][c].y += xk[r] * w4.y;
                    acc[r][c].z += xk[r] * w4.z;
                    acc[r][c].w += xk[r] * w4.w;
                }
            }
        }
    }

    #pragma unroll
    for (int r = 0; r < 4; ++r) {
        int rr = row0 + r;
        if (rr < n) {
            float4* op = (float4*)(out + (size_t)rr * 64 + cq * 16);
            #pragma unroll
            for (int c = 0; c < 4; ++c) op[c] = acc[r][c];
        }
    }
}

// -------- fused CSR aggregation (64 feats): one wave per dst row, lane = feat --------
// inner loop unrolled x4: 4 independent gathers in flight, accumulation order
// preserved exactly (sequential adds).
__global__ void __launch_bounds__(256) agg64_fused(const int* __restrict__ rowptr,
                                                   const int* __restrict__ col,
                                                   const float* __restrict__ enormp,
                                                   const float* __restrict__ hpre,
                                                   const float* __restrict__ dinv,
                                                   const float* __restrict__ bias,
                                                   float* __restrict__ hout, int n) {
    int gid = blockIdx.x * 256 + threadIdx.x;
    int row = gid >> 6;
    int lane = gid & 63;
    if (row >= n) return;
    int r0 = rowptr[row], r1 = rowptr[row + 1];
    float acc = 0.0f;
    for (int base = r0; base < r1; base += 64) {
        int e = base + lane;
        int cv = 0; float ev = 0.0f;
        if (e < r1) { cv = col[e]; ev = enormp[e]; }
        int m = r1 - base; if (m > 64) m = 64;
        int j = 0;
        for (; j + 4 <= m; j += 4) {
            int s0 = __shfl(cv, j, 64);
            int s1 = __shfl(cv, j + 1, 64);
            int s2 = __shfl(cv, j + 2, 64);
            int s3 = __shfl(cv, j + 3, 64);
            float c0 = __shfl(ev, j, 64);
            float c1 = __shfl(ev, j + 1, 64);
            float c2 = __shfl(ev, j + 2, 64);
            float c3 = __shfl(ev, j + 3, 64);
            float v0 = hpre[(size_t)s0 * 64 + lane];
            float v1 = hpre[(size_t)s1 * 64 + lane];
            float v2 = hpre[(size_t)s2 * 64 + lane];
            float v3 = hpre[(size_t)s3 * 64 + lane];
            acc += c0 * v0;
            acc += c1 * v1;
            acc += c2 * v2;
            acc += c3 * v3;
        }
        for (; j < m; ++j) {
            int s = __shfl(cv, j, 64);
            float coef = __shfl(ev, j, 64);
            acc += coef * hpre[(size_t)s * 64 + lane];
        }
    }
    float dv = dinv[row];
    hout[gid] = tanhf(acc + dv * dv * hpre[(size_t)row * 64 + lane] + bias[lane]);
}

// ---------------- h2 @ W2 (64 -> 1), one wave per row ----------------
__global__ void gemv64(const float* __restrict__ h, const float* __restrict__ w,
                       float* __restrict__ out, int n) {
    int gid = blockIdx.x * blockDim.x + threadIdx.x;
    int row = gid >> 6;
    int lane = gid & 63;
    if (row >= n) return;
    float v = h[(size_t)row * 64 + lane] * w[lane];
    for (int off = 32; off > 0; off >>= 1) v += __shfl_down(v, off, 64);
    if (lane == 0) out[row] = v;
}

// -------- fused CSR aggregation (1 feat): one thread per dst row --------
__global__ void agg1_fused(const int* __restrict__ rowptr, const int* __restrict__ col,
                           const float* __restrict__ enormp, const float* __restrict__ hpre3,
                           const float* __restrict__ dinv, const float* __restrict__ b2,
                           float* __restrict__ h3, int n) {
    int i = blockIdx.x * blockDim.x + threadIdx.x;
    if (i >= n) return;
    float acc = 0.0f;
    int r1 = rowptr[i + 1];
    for (int e = rowptr[i]; e < r1; ++e) acc += enormp[e] * hpre3[col[e]];
    float dv = dinv[i];
    h3[i] = tanhf(acc + dv * dv * hpre3[i] + b2[0]);
}

// ---------------- group compaction: deterministic counting sort, no global atomics ----
__global__ void __launch_bounds__(256) grp_hist(const int* __restrict__ group,
                                                int* __restrict__ bcnt, int n) {
    __shared__ int lh[NG];
    int b = blockIdx.x, t = threadIdx.x;
    if (t < NG) lh[t] = 0;
    __syncthreads();
    int i = b * 256 + t;
    if (i < n) atomicAdd(&lh[group[i]], 1);
    __syncthreads();
    if (t < NG) bcnt[t * NBLK + b] = lh[t];
}

// one block per group: exclusive scan of bcnt[g][0..NBLK) -> boff; total -> cnt[g]
__global__ void __launch_bounds__(512) grp_scan(const int* __restrict__ bcnt,
                                                int* __restrict__ boff,
                                                int* __restrict__ cnt) {
    __shared__ int s[512];
    int g = blockIdx.x, t = threadIdx.x;
    int orig = t < NBLK ? bcnt[g * NBLK + t] : 0;
    s[t] = orig;
    __syncthreads();
    for (int o = 1; o < 512; o <<= 1) {
        int v = t >= o ? s[t - o] : 0;
        __syncthreads();
        s[t] += v;
        __syncthreads();
    }
    if (t < NBLK) boff[g * NBLK + t] = s[t] - orig;
    if (t == 511) cnt[g] = s[NBLK - 1] > CAP ? CAP : s[NBLK - 1];
}

__global__ void __launch_bounds__(256) grp_fill(const int* __restrict__ group,
                                                const int* __restrict__ boff,
                                                int* __restrict__ lists, int n) {
    __shared__ int lcur[NG];
    int b = blockIdx.x, t = threadIdx.x;
    if (t < NG) lcur[t] = 0;
    __syncthreads();
    int i = b * 256 + t;
    if (i < n) {
        int g = group[i];
        int p = atomicAdd(&lcur[g], 1);
        int pos = boff[g * NBLK + b] + p;
        if (pos < CAP) lists[g * CAP + pos] = i;
    }
}

// ---------------- per-group top-K by h3: iterative selection in registers ----------
// key = (monotone_float_bits(h3) << 32) | ~node  — value desc, index asc; unique.
__device__ __forceinline__ unsigned int fkey(float v) {
    unsigned int b = __float_as_uint(v);
    return (b & 0x80000000u) ? ~b : (b | 0x80000000u);
}

__global__ void __launch_bounds__(256) topk_kernel(const int* __restrict__ cnt,
                                                   const int* __restrict__ lists,
                                                   const float* __restrict__ h3,
                                                   int* __restrict__ topk) {
    __shared__ unsigned long long wmax[4];
    __shared__ unsigned long long winner;
    int g = blockIdx.x;
    int tid = threadIdx.x;
    int lane = tid & 63, wid = tid >> 6;
    int c = cnt[g];
    if (c > CAP) c = CAP;

    unsigned long long key[SLOTS];
    #pragma unroll
    for (int s = 0; s < SLOTS; ++s) {
        int e = s * 256 + tid;
        if (e < c) {
            int node = lists[g * CAP + e];
            key[s] = ((unsigned long long)fkey(h3[node]) << 32) | (unsigned int)(~node);
        } else {
            key[s] = 0ull;
        }
    }

    for (int k = 0; k < KTOP; ++k) {
        unsigned long long best = 0ull;
        #pragma unroll
        for (int s = 0; s < SLOTS; ++s) best = key[s] > best ? key[s] : best;
        #pragma unroll
        for (int off = 32; off > 0; off >>= 1) {
            unsigned long long o = __shfl_down(best, off, 64);
            best = o > best ? o : best;
        }
        if (lane == 0) wmax[wid] = best;
        __syncthreads();
        if (tid == 0) {
            unsigned long long b = wmax[0];
            for (int w = 1; w < 4; ++w) b = wmax[w] > b ? wmax[w] : b;
            winner = b;
            topk[g * KTOP + k] = ~(int)(unsigned int)b;
        }
        __syncthreads();
        unsigned long long w = winner;
        #pragma unroll
        for (int s = 0; s < SLOTS; ++s) if (key[s] == w) key[s] = 0ull;
        __syncthreads();
    }
}

// ---------------- fused sort-pool gather + conv1 + maxpool + conv2 ----------------
__global__ void __launch_bounds__(256) pool_conv(const float* __restrict__ h1,
                                                 const float* __restrict__ h2,
                                                 const float* __restrict__ h3,
                                                 const int* __restrict__ topk,
                                                 const float* __restrict__ c1w,
                                                 const float* __restrict__ c1b,
                                                 const float* __restrict__ c2w,
                                                 const float* __restrict__ c2b,
                                                 float* __restrict__ out) {
    __shared__ float sfeat[KTOP * DFLAT];
    __shared__ float sy[NC1 * KTOP];
    __shared__ float sm[NC1 * (KTOP / 2)];
    int g = blockIdx.x;
    int tid = threadIdx.x;

    for (int t = tid; t < KTOP * DFLAT; t += blockDim.x) {
        int k = t / DFLAT, d = t - k * DFLAT;
        int node = topk[g * KTOP + k];
        float v;
        if (d < 64)        v = h1[(size_t)node * 64 + d];
        else if (d < 128)  v = h2[(size_t)node * 64 + (d - 64)];
        else               v = h3[node];
        sfeat[t] = v;
    }
    __syncthreads();

    for (int t = tid; t < NC1 * KTOP; t += blockDim.x) {
        int c = t / KTOP, k = t - c * KTOP;
        float acc = c1b[c];
        const float* w = c1w + c * DFLAT;
        const float* f = sfeat + k * DFLAT;
        for (int d = 0; d < DFLAT; ++d) acc += f[d] * w[d];
        sy[c * KTOP + k] = fmaxf(acc, 0.0f);
    }
    __syncthreads();

    for (int t = tid; t < NC1 * (KTOP / 2); t += blockDim.x) {
        int c = t / (KTOP / 2), j = t - c * (KTOP / 2);
        sm[t] = fmaxf(sy[c * KTOP + 2 * j], sy[c * KTOP + 2 * j + 1]);
    }
    __syncthreads();

    for (int t = tid; t < NC2 * TOUT; t += blockDim.x) {
        int c2 = t / TOUT, tt = t - c2 * TOUT;
        float acc = c2b[c2];
        for (int c1i = 0; c1i < NC1; ++c1i) {
            const float* w = c2w + (c2 * NC1 + c1i) * KSZ;
            const float* m = sm + c1i * (KTOP / 2) + tt;
            for (int s = 0; s < KSZ; ++s) acc += m[s] * w[s];
        }
        out[g * NC2 * TOUT + t] += fmaxf(acc, 0.0f);
    }
}

// ---------------- host ----------------
static inline size_t align256(size_t x) { return (x + 255) & ~(size_t)255; }

extern "C" void kernel_launch(void* const* d_in, const int* in_sizes, int n_in,
                              void* d_out, int out_size, void* d_ws, size_t ws_size,
                              hipStream_t stream) {
    const float* x       = (const float*)d_in[0];
    const int*   eidx    = (const int*)d_in[1];    // [R,2,E]
    const float* ew      = (const float*)d_in[2];  // [R,E]
    const int*   group   = (const int*)d_in[3];    // [N]
    const float* W0      = (const float*)d_in[4];  // [R,128,64]
    const float* b0      = (const float*)d_in[5];
    const float* W1      = (const float*)d_in[6];  // [R,64,64]
    const float* b1      = (const float*)d_in[7];
    const float* W2      = (const float*)d_in[8];  // [R,64,1]
    const float* b2      = (const float*)d_in[9];
    const float* c1w     = (const float*)d_in[10];
    const float* c1b     = (const float*)d_in[11];
    const float* c2w     = (const float*)d_in[12];
    const float* c2b     = (const float*)d_in[13];
    float* out = (float*)d_out;

    char* ws = (char*)d_ws;
    size_t off = 0;
    float* dinv    = (float*)(ws + off); off = align256(off + (size_t)N_NODES * 4);
    int*   rowptr  = (int*)(ws + off);   off = align256(off + (size_t)(N_NODES + 1) * 4);
    int*   fillpos = (int*)(ws + off);   off = align256(off + (size_t)N_NODES * 4);
    int*   ccnt    = (int*)(ws + off);   off = align256(off + (size_t)N_NODES * 4);
    int*   bsum    = (int*)(ws + off);   off = align256(off + (size_t)512 * 4);
    int*   col     = (int*)(ws + off);   off = align256(off + (size_t)E_EDGES * 4);
    float* ewp     = (float*)(ws + off); off = align256(off + (size_t)E_EDGES * 4);
    int*   eorig   = (int*)(ws + off);   off = align256(off + (size_t)E_EDGES * 4);
    float* enormp  = (float*)(ws + off); off = align256(off + (size_t)E_EDGES * 4);
    float* hpre    = (float*)(ws + off); off = align256(off + (size_t)N_NODES * 64 * 4);
    float* h1      = (float*)(ws + off); off = align256(off + (size_t)N_NODES * 64 * 4);
    float* h2      = (float*)(ws + off); off = align256(off + (size_t)N_NODES * 64 * 4);
    float* hpre3   = (float*)(ws + off); off = align256(off + (size_t)N_NODES * 4);
    float* h3      = (float*)(ws + off); off = align256(off + (size_t)N_NODES * 4);
    int*   cnt     = (int*)(ws + off);   off = align256(off + (size_t)NG * 4);
    int*   lists   = (int*)(ws + off);   off = align256(off + (size_t)NG * CAP * 4);
    int*   topk    = (int*)(ws + off);   off = align256(off + (size_t)NG * KTOP * 4);
    int*   bcnt    = (int*)(ws + off);   off = align256(off + (size_t)NG * NBLK * 4);
    int*   boff    = (int*)(ws + off);   off = align256(off + (size_t)NG * NBLK * 4);
    (void)ws_size;

    const int B = 256;
    const int nOut = NG * NC2 * TOUT;
    const int gN   = (N_NODES + B - 1) / B;           // 391
    const int gE   = (E_EDGES + B - 1) / B;           // 6250
    const int gW   = (N_NODES * 64 + B - 1) / B;      // 25000
    const int gT   = (N_NODES + 255) / 256;           // gemm_tile

    zero_f32<<<(nOut + B - 1) / B, B, 0, stream>>>(out, nOut);

    // group compaction: deterministic counting sort, once per launch
    grp_hist<<<NBLK, B, 0, stream>>>(group, bcnt, N_NODES);
    grp_scan<<<NG, 512, 0, stream>>>(bcnt, boff, cnt);
    grp_fill<<<NBLK, B, 0, stream>>>(group, boff, lists, N_NODES);

    for (int r = 0; r < R_REL; ++r) {
        const int* src = eidx + (size_t)r * 2 * E_EDGES;
        const int* dst = src + E_EDGES;
        const float* ewr = ew + (size_t)r * E_EDGES;

        // ---- CSR build (stable in original edge order) ----
        zero_i32<<<gN, B, 0, stream>>>(ccnt, N_NODES);
        hist_kernel<<<gE, B, 0, stream>>>(dst, ccnt, E_EDGES);
        block_sum<<<gN, B, 0, stream>>>(ccnt, bsum, N_NODES);
        scan_bsum<<<1, 512, 0, stream>>>(bsum, gN);
        scan_blocks<<<gN, B, 0, stream>>>(ccnt, bsum, rowptr, N_NODES);
        copy_i32<<<gN, B, 0, stream>>>(rowptr, fillpos, N_NODES);
        fill_csr<<<gE, B, 0, stream>>>(src, dst, ewr, fillpos, col, ewp, eorig, E_EDGES);
        sort_rows<<<gN, B, 0, stream>>>(rowptr, col, ewp, eorig, N_NODES);
        deg_dinv<<<gN, B, 0, stream>>>(rowptr, ewp, dinv, N_NODES);
        enorm_csr<<<gN, B, 0, stream>>>(rowptr, col, ewp, dinv, enormp, N_NODES);

        // layer 1
        gemm_tile<128><<<gT, B, 0, stream>>>(x, W0 + (size_t)r * 128 * 64, hpre, N_NODES);
        agg64_fused<<<gW, B, 0, stream>>>(rowptr, col, enormp, hpre, dinv,
                                          b0 + (size_t)r * 64, h1, N_NODES);
        // layer 2
        gemm_tile<64><<<gT, B, 0, stream>>>(h1, W1 + (size_t)r * 64 * 64, hpre, N_NODES);
        agg64_fused<<<gW, B, 0, stream>>>(rowptr, col, enormp, hpre, dinv,
                                          b1 + (size_t)r * 64, h2, N_NODES);
        // layer 3
        gemv64<<<gW, B, 0, stream>>>(h2, W2 + (size_t)r * 64, hpre3, N_NODES);
        agg1_fused<<<gN, B, 0, stream>>>(rowptr, col, enormp, hpre3, dinv, b2 + r, h3, N_NODES);

        // sort pooling + convs
        topk_kernel<<<NG, B, 0, stream>>>(cnt, lists, h3, topk);
        pool_conv<<<NG, B, 0, stream>>>(h1, h2, h3, topk, c1w, c1b, c2w, c2b, out);
    }
}